// Round 1
// baseline (2133.501 us; speedup 1.0000x reference)
//
#include <hip/hip_runtime.h>
#include <stdint.h>

#define BATCH 4
#define HEADS 16
#define SEQ   2048
#define DIM   64
#define QT    16            // q rows per workgroup
#define KT    64            // k columns per staged tile
#define PS_STRIDE  2056     // 2048+8 bf16 -> 4112 B rows (16B aligned, 2-way-free E writes)
#define KST_STRIDE 72       // 64+8 bf16 -> 144 B rows (16B aligned, conflict-minimal b128)

typedef __attribute__((ext_vector_type(8))) short  short8;   // 8 x bf16 bits (MFMA A/B frag)
typedef __attribute__((ext_vector_type(4))) float  floatx4;  // MFMA C/D frag / vector IO

static __device__ __forceinline__ unsigned short f32_to_bf16_bits(float f) {
    union { float f; uint32_t u; } x; x.f = f;
    uint32_t r = x.u + 0x7FFFu + ((x.u >> 16) & 1u);   // RNE
    return (unsigned short)(r >> 16);
}
static __device__ __forceinline__ float bf16_bits_to_f32(unsigned short h) {
    union { uint32_t u; float f; } x; x.u = ((uint32_t)h) << 16;
    return x.f;
}

__global__ __launch_bounds__(256) void attn_fused_kernel(
    const float* __restrict__ q, const float* __restrict__ k,
    const float* __restrict__ v, const int* __restrict__ mask,
    float* __restrict__ out, float* __restrict__ score)
{
    __shared__ __align__(16) unsigned short Ps[QT][PS_STRIDE];    // unnormalized exp, bf16
    __shared__ __align__(16) unsigned short Kst[KT][KST_STRIDE];  // K tile, then V^T tile
    __shared__ float lsum[QT];                                    // row sums -> reciprocals

    const int tid  = threadIdx.x;
    const int w    = tid >> 6;        // wave 0..3 -> 16-col n-slice of the 64-wide k-tile
    const int lane = tid & 63;
    const int quad = lane >> 4;       // 0..3
    const int nl   = lane & 15;

    const int qt = blockIdx.x;        // 0..127  (q tile)
    const int bh = blockIdx.y;        // 0..63   (b*H+h) — x-fastest dispatch shares K/V in L2
    const int b  = bh >> 4;           // H = 16
    const int q0 = qt * QT;

    const float* qbase = q + ((size_t)bh * SEQ + q0) * DIM;
    const float* kbase = k + (size_t)bh * SEQ * DIM;
    const float* vbase = v + (size_t)bh * SEQ * DIM;
    const int*   mbase = mask + ((size_t)b * SEQ + q0) * SEQ;

    if (tid < QT) lsum[tid] = 0.0f;

    // ---- Q A-fragments once per block: A[m=nl][k=quad*8+j], bf16, 2 ksteps of 32 ----
    short8 aq[2];
    {
        const float* qrow = qbase + (size_t)nl * DIM + quad * 8;
        #pragma unroll
        for (int s = 0; s < 2; ++s) {
            const floatx4* p4 = (const floatx4*)(qrow + s * 32);
            floatx4 f0 = p4[0], f1 = p4[1];
            short8 a;
            #pragma unroll
            for (int j = 0; j < 4; ++j) {
                a[j]     = (short)f32_to_bf16_bits(f0[j]);
                a[j + 4] = (short)f32_to_bf16_bits(f1[j]);
            }
            aq[s] = a;
        }
    }

    const int stg_row = tid >> 2;        // 0..63
    const int stg_cb  = (tid & 3) * 16;  // 0,16,32,48

    float rs[4] = {0.f, 0.f, 0.f, 0.f};

    // ================= Phase 1: E = exp(mask ? QK^T/8 : 1e-12) into Ps =================
    for (int kt = 0; kt < SEQ / KT; ++kt) {
        const int k0 = kt * KT;
        __syncthreads();                      // staging buffer free
        // mask prefetch (consumed after MFMA; latency hidden behind staging)
        int mreg[4];
        #pragma unroll
        for (int i = 0; i < 4; ++i)
            mreg[i] = mbase[(size_t)(quad * 4 + i) * SEQ + k0 + w * 16 + nl];
        // stage K tile [kk][d] -> bf16 (coalesced 4KB/wave global reads)
        {
            const floatx4* src = (const floatx4*)(kbase + (size_t)(k0 + stg_row) * DIM + stg_cb);
            floatx4 f0 = src[0], f1 = src[1], f2 = src[2], f3 = src[3];
            short8 t0, t1;
            #pragma unroll
            for (int j = 0; j < 4; ++j) {
                t0[j]     = (short)f32_to_bf16_bits(f0[j]);
                t0[j + 4] = (short)f32_to_bf16_bits(f1[j]);
                t1[j]     = (short)f32_to_bf16_bits(f2[j]);
                t1[j + 4] = (short)f32_to_bf16_bits(f3[j]);
            }
            *(short8*)&Kst[stg_row][stg_cb]     = t0;
            *(short8*)&Kst[stg_row][stg_cb + 8] = t1;
        }
        __syncthreads();
        floatx4 acc = {0.f, 0.f, 0.f, 0.f};
        #pragma unroll
        for (int s = 0; s < 2; ++s) {
            short8 bfrag = *(const short8*)&Kst[w * 16 + nl][s * 32 + quad * 8];
            acc = __builtin_amdgcn_mfma_f32_16x16x32_bf16(aq[s], bfrag, acc, 0, 0, 0);
        }
        // C/D: row = quad*4+i (q), col = nl (k-col within this wave's 16-slice)
        #pragma unroll
        for (int i = 0; i < 4; ++i) {
            float e = (mreg[i] != 0) ? __expf(acc[i] * 0.125f) : 1.0f;  // exp(1e-12)==1.0f
            rs[i] += e;
            Ps[quad * 4 + i][k0 + w * 16 + nl] = f32_to_bf16_bits(e);
        }
    }

    // ================= Phase 2: row sums -> reciprocals =================
    #pragma unroll
    for (int i = 0; i < 4; ++i) {
        float x = rs[i];
        x += __shfl_xor(x, 1, 16);
        x += __shfl_xor(x, 2, 16);
        x += __shfl_xor(x, 4, 16);
        x += __shfl_xor(x, 8, 16);
        if (nl == 0) atomicAdd(&lsum[quad * 4 + i], x);
    }
    __syncthreads();
    if (tid < QT) lsum[tid] = 1.0f / lsum[tid];
    __syncthreads();

    // ================= Phase 3: O = E @ V (normalize at the end) =================
    floatx4 oacc = {0.f, 0.f, 0.f, 0.f};
    for (int kt = 0; kt < SEQ / KT; ++kt) {
        const int k0 = kt * KT;
        __syncthreads();
        // stage V^T tile: Kst[d][kk] = V[k0+kk][d]  (scalar b16 transpose writes)
        {
            const floatx4* src = (const floatx4*)(vbase + (size_t)(k0 + stg_row) * DIM + stg_cb);
            floatx4 f0 = src[0], f1 = src[1], f2 = src[2], f3 = src[3];
            #pragma unroll
            for (int j = 0; j < 4; ++j) {
                Kst[stg_cb + j][stg_row]      = f32_to_bf16_bits(f0[j]);
                Kst[stg_cb + 4 + j][stg_row]  = f32_to_bf16_bits(f1[j]);
                Kst[stg_cb + 8 + j][stg_row]  = f32_to_bf16_bits(f2[j]);
                Kst[stg_cb + 12 + j][stg_row] = f32_to_bf16_bits(f3[j]);
            }
        }
        __syncthreads();
        #pragma unroll
        for (int s = 0; s < 2; ++s) {
            short8 afrag = *(const short8*)&Ps[nl][k0 + s * 32 + quad * 8];          // A[m=q][k=s]
            short8 bfrag = *(const short8*)&Kst[w * 16 + nl][s * 32 + quad * 8];     // B[n=d][k=s]
            oacc = __builtin_amdgcn_mfma_f32_16x16x32_bf16(afrag, bfrag, oacc, 0, 0, 0);
        }
    }

    // ================= Phase 4: write O (normalized) =================
    #pragma unroll
    for (int i = 0; i < 4; ++i) {
        const int row = quad * 4 + i;
        out[((size_t)bh * SEQ + q0 + row) * DIM + w * 16 + nl] = oacc[i] * lsum[row];
    }

    // ================= Phase 5: write normalized score, coalesced float4 =================
    float* sbase = score + ((size_t)bh * SEQ + q0) * SEQ;
    for (int it = 0; it < 2 * QT; ++it) {
        const int row     = it >> 1;
        const int colbase = (it & 1) * 1024 + tid * 4;
        const float rv = lsum[row];
        const uint32_t* pp = (const uint32_t*)&Ps[row][colbase];
        uint32_t w0 = pp[0], w1 = pp[1];
        floatx4 val;
        val[0] = bf16_bits_to_f32((unsigned short)(w0 & 0xFFFFu)) * rv;
        val[1] = bf16_bits_to_f32((unsigned short)(w0 >> 16))     * rv;
        val[2] = bf16_bits_to_f32((unsigned short)(w1 & 0xFFFFu)) * rv;
        val[3] = bf16_bits_to_f32((unsigned short)(w1 >> 16))     * rv;
        *(floatx4*)&sbase[(size_t)row * SEQ + colbase] = val;
    }
}

extern "C" void kernel_launch(void* const* d_in, const int* in_sizes, int n_in,
                              void* d_out, int out_size, void* d_ws, size_t ws_size,
                              hipStream_t stream) {
    (void)in_sizes; (void)n_in; (void)out_size; (void)d_ws; (void)ws_size;
    const float* q    = (const float*)d_in[0];
    const float* k    = (const float*)d_in[1];
    const float* v    = (const float*)d_in[2];
    const int*   mask = (const int*)d_in[3];
    float* out   = (float*)d_out;
    float* score = out + (size_t)BATCH * HEADS * SEQ * DIM;   // outputs concatenated: [out | score]
    dim3 grid(SEQ / QT, BATCH * HEADS);
    attn_fused_kernel<<<grid, dim3(256), 0, stream>>>(q, k, v, mask, out, score);
}